// Round 4
// baseline (156.422 us; speedup 1.0000x reference)
//
#include <hip/hip_runtime.h>
#include <math.h>

#define T_LEN   16384
#define NBATCH  8
#define NBLK    6
#define TILE    256
#define HALO    63
#define NTHR    768          // 12 waves; each wave owns 32 rows (2 m-tiles)
#define NWAVE   12
#define NROWS   384          // TILE + 2*HALO = 382, padded to 384
#define NTILES  64
#define HS      18           // f16 row stride in dwords (72 B)
#define HBUF    (NROWS * HS) // one h buffer in dwords

// workspace layout (dwords)
#define WS_CONV 0             // [i6][tap3][nt4][lane64][dw4] = 18432
#define WS_SKIP 18432         // [i6][nt2][lane64][dw4]      = 3072
#define WS_FIN  21504         // [nt2][lane64][dw4]          = 512
#define WS_LOG  22016         // 16 floats logits
#define WS_CNT  22032         // 1 uint completion counter
#define PREP_N  22016
#define PREP_TOT 22036

// per-iter LDS weight stage: 12 conv chunks + 2 skip chunks, 256 dw each
#define STG_CONV 0            // [tap3][nt4][lane64][dw4] = 3072 dw
#define STG_SKIP 3072         // [nt2][lane64][dw4]       = 512 dw
#define STG_TOT  3584         // 14336 B

typedef _Float16 half8 __attribute__((ext_vector_type(8)));
typedef __fp16  fp16x2 __attribute__((ext_vector_type(2)));
typedef float f32x4  __attribute__((ext_vector_type(4)));

union HPK { unsigned u; _Float16 h[2]; fp16x2 pk; };
union AFR { uint2 u2[2]; half8 v; };

__device__ __forceinline__ unsigned packh(float a, float b) {   // 1x v_cvt_pkrtz_f16_f32
    HPK r; r.pk = __builtin_amdgcn_cvt_pkrtz(a, b); return r.u;
}
__device__ __forceinline__ float f16a(unsigned p) { HPK r; r.u = p; return (float)r.h[0]; }
__device__ __forceinline__ float f16b(unsigned p) { HPK r; r.u = p; return (float)r.h[1]; }

// tanh(a)*sigmoid(b), overflow-safe, 3 quarter-rate ops (2 exp + 1 rcp)
__device__ __forceinline__ float gated(float a, float b) {
    float ea  = __expf(-2.0f * fabsf(a));      // (0,1]
    float fb  = __expf(-b);
    float num = 1.0f - ea;
    float den = (1.0f + ea) * (1.0f + fb);
    float t   = num * __builtin_amdgcn_rcpf(den);
    return __builtin_copysignf(t, a);
}
__device__ __forceinline__ float relu(float x) { return fmaxf(x, 0.0f); }

// async global->LDS DMA, 16B per lane, wave-linear dest (base + lane*16)
__device__ __forceinline__ void gl_lds16(const unsigned* g, unsigned* l) {
    __builtin_amdgcn_global_load_lds(
        (const __attribute__((address_space(1))) void*)g,
        (__attribute__((address_space(3))) void*)l, 16, 0, 0);
}

#define MFMA(a, b, c) __builtin_amdgcn_mfma_f32_16x16x32_f16((a), (b), (c), 0, 0, 0)

// ---------------- weight prep: fp32 -> f16 B-fragments (permuted cols) ----------------
__global__ void wavenet_prep(const float* __restrict__ wt, const float* __restrict__ wsg,
                             const float* __restrict__ wsk, const float* __restrict__ wfin,
                             unsigned* __restrict__ out)
{
    int id = blockIdx.x * 256 + threadIdx.x;
    if (id >= PREP_TOT) return;
    if (id >= PREP_N) { out[id] = 0u; return; }   // zero logits + counter
    int dw = id & 3, lane = (id >> 2) & 63;
    int g = lane >> 4, nlo = lane & 15;
    int k0 = g * 8 + dw * 2, k1 = k0 + 1;
    float v0, v1;
    if (id < WS_SKIP) {
        int nt = (id >> 8) & 3; int q = id >> 10;
        int tap = q % 3, i = q / 3;
        int chan = 2 * nlo + (nt & 1);
        const float* src = (nt < 2) ? wt : wsg;
        v0 = src[((i * 3 + tap) * 32 + k0) * 32 + chan];
        v1 = src[((i * 3 + tap) * 32 + k1) * 32 + chan];
    } else if (id < WS_FIN) {
        int t = id - WS_SKIP;
        int nt = (t >> 8) & 1; int i = t >> 9;
        int chan = 2 * nlo + nt;
        v0 = wsk[(i * 32 + k0) * 32 + chan];
        v1 = wsk[(i * 32 + k1) * 32 + chan];
    } else {
        int t = id - WS_FIN;
        int nt = (t >> 8) & 1;
        int chan = 2 * nlo + nt;
        v0 = wfin[k0 * 32 + chan];
        v1 = wfin[k1 * 32 + chan];
    }
    HPK r; r.h[0] = (_Float16)v0; r.h[1] = (_Float16)v1;   // RNE for weights
    out[id] = r.u;
}

// ---------------- main fused kernel ----------------
// (768,6): cap 85 unified regs/wave -> 6 waves/SIMD -> 2 blocks/CU (24 waves).
// Per-m conv split keeps only 16 acc AGPRs live (un-split 32-acc spills, r16).
// r20: per-iter weights staged via global_load_lds (prefetch 1 iter ahead).
// r21 (this round): 2-segment software pipeline. The coarse asm memory fence
// (which serialized seg1's conv behind seg0's epilogue) is replaced by
// VOLATILE z-writes/za-reads: volatile<->volatile program order + same-wave
// in-order DS gives the z->za ordering (a cross-lane exchange per-thread alias
// analysis cannot see) while letting the scheduler overlap conv(1) with
// gates(0) and hide both za round trips under the staging barrier.
__global__ __launch_bounds__(NTHR, 6)
void wavenet_main(const float* __restrict__ x,
                  const float* __restrict__ w_init, const float* __restrict__ b_init,
                  const float* __restrict__ b_tanh, const float* __restrict__ b_sig,
                  const float* __restrict__ b_skip, const float* __restrict__ b_final,
                  const float* __restrict__ b_dense,
                  const float* __restrict__ w_dense,
                  const unsigned* __restrict__ wsB,
                  float* __restrict__ logits, unsigned* __restrict__ counter,
                  float* __restrict__ out)
{
    __shared__ unsigned h_pack[2 * HBUF];      // double-buffered, 55296 B
    __shared__ unsigned wstage[STG_TOT];       // per-iter weight stage, 14336 B
    __shared__ float x_s[NROWS];               // 1536 B
    __shared__ float bias_s[3 * NBLK * 32];    // [t/s/k][i][ch], 2304 B
    __shared__ float wib_s[64];                // w_init[0..31], b_init[0..31]
    __shared__ float red[NWAVE][2];

    const int tid  = threadIdx.x;
    const int lane = tid & 63;
    const int wv   = tid >> 6;               // 0..11; wave owns rows [wv*32, wv*32+32)
    const int tile = blockIdx.x & (NTILES - 1);
    const int b    = blockIdx.x >> 6;
    const int col0 = lane & 15;
    const int g4   = lane >> 4;

    // stage iter-`it` weights: wave wv takes conv chunk wv, waves 0/1 also skip chunks
    #define STAGE_ITER(it) do {                                                   \
        const unsigned* _s = wsB + (it) * 3072 + wv * 256 + (lane << 2);          \
        gl_lds16(_s, wstage + wv * 256 + (lane << 2));                            \
        if (wv < 2) {                                                             \
            const unsigned* _s2 = wsB + WS_SKIP + (it) * 512 + wv * 256 + (lane << 2); \
            gl_lds16(_s2, wstage + STG_SKIP + wv * 256 + (lane << 2));            \
        }                                                                         \
    } while (0)

    // conv GEMM for one 16-row segment: [16 x 96] x [96 x 64], single-product f16
    #define CONV_SEG(ROW0, ACC, HOLD) do {                                        \
        _Pragma("unroll")                                                         \
        for (int tap = 0; tap < 3; ++tap) {                                       \
            half8 bw[4];                                                          \
            _Pragma("unroll")                                                     \
            for (int nt = 0; nt < 4; ++nt)                                        \
                bw[nt] = *(const half8*)(wstage + (tap * 4 + nt) * 256 + (lane << 2)); \
            int r = (ROW0) + (tap - 1) * d + col0;                                \
            r = r < 0 ? 0 : (r > NROWS - 1 ? NROWS - 1 : r);                      \
            const unsigned* hp = cur + r * HS + g4 * 4;                           \
            AFR a; a.u2[0] = *(const uint2*)hp; a.u2[1] = *(const uint2*)(hp + 2);\
            _Pragma("unroll")                                                     \
            for (int nt = 0; nt < 4; ++nt)                                        \
                (ACC)[nt] = MFMA(a.v, bw[nt], (ACC)[nt]);                         \
        }                                                                         \
        _Pragma("unroll")                                                         \
        for (int reg = 0; reg < 4; ++reg)                                         \
            (HOLD)[reg] = cur[((ROW0) + 4 * g4 + reg) * HS + col0];               \
    } while (0)

    // gates + volatile z-write for one segment (consumes ACC into 4 packed dwords)
    #define GATE_Z(ROW0, ACC) do {                                                \
        _Pragma("unroll")                                                         \
        for (int reg = 0; reg < 4; ++reg) {                                       \
            float z0 = gated((ACC)[0][reg] + btv.x, (ACC)[2][reg] + bsv.x);       \
            float z1 = gated((ACC)[1][reg] + btv.y, (ACC)[3][reg] + bsv.y);       \
            vnxt[((ROW0) + 4 * g4 + reg) * HS + col0] = packh(z0, z1);            \
        }                                                                         \
    } while (0)

    // volatile za gather (A-fragment of z for the skip MFMA)
    #define ZA_READ(ROW0, AZ) do {                                                \
        const volatile unsigned* _p =                                             \
            (const volatile unsigned*)(nxt + ((ROW0) + col0) * HS + g4 * 4);      \
        unsigned _w0 = _p[0], _w1 = _p[1], _w2 = _p[2], _w3 = _p[3];              \
        (AZ).u2[0] = make_uint2(_w0, _w1); (AZ).u2[1] = make_uint2(_w2, _w3);     \
    } while (0)

    // skip epilogue + h update into nxt (own rows only)
    #define H_UPDATE(ROW0, HOLD, S0, S1, ILAST) do {                              \
        _Pragma("unroll")                                                         \
        for (int reg = 0; reg < 4; ++reg) {                                       \
            const int row = (ROW0) + 4 * g4 + reg;                                \
            float sk0 = relu((S0)[reg] + bkv.x);                                  \
            float sk1 = relu((S1)[reg] + bkv.y);                                  \
            unsigned ph = (HOLD)[reg];                                            \
            float h0n = sk0 + f16a(ph);                                           \
            float h1n = sk1 + f16b(ph);                                           \
            unsigned pk;                                                          \
            if (!(ILAST)) {                                                       \
                int tgr = tile * TILE - HALO + row;                               \
                bool vr = (tgr >= 0) && (tgr < T_LEN);                            \
                pk = vr ? packh(h0n, h1n) : 0u;                                   \
            } else {                                                              \
                float2 wiv = *(const float2*)&wib_s[2 * col0];                    \
                float2 biv = *(const float2*)&wib_s[32 + 2 * col0];               \
                float xr  = x_s[row];                                             \
                float hi0 = relu(fmaf(xr, wiv.x, biv.x));                         \
                float hi1 = relu(fmaf(xr, wiv.y, biv.y));                         \
                pk = packh(relu(h0n - hi0), relu(h1n - hi1));                     \
            }                                                                     \
            nxt[row * HS + col0] = pk;                                            \
        }                                                                         \
    } while (0)

    // ---- issue DMA for iter-0 weights immediately (lands before first barrier drain) ----
    STAGE_ITER(0);

    // ---- stage biases + init weights into LDS (once) ----
    if (tid < 3 * NBLK * 32) {
        int which = tid / (NBLK * 32), r = tid % (NBLK * 32);
        float v = (which == 0) ? b_tanh[r] : (which == 1) ? b_sig[r] : b_skip[r];
        bias_s[tid] = v;
    } else if (tid < 3 * NBLK * 32 + 64) {
        int r = tid - 3 * NBLK * 32;
        wib_s[r] = (r < 32) ? w_init[r] : b_init[r - 32];
    }

    // ---- init conv (CIN=1) -> f16 h in buf0; 2 threads per row ----
    {
        int j    = tid >> 1;                 // row 0..383
        int half = tid & 1;                  // dwords half*8 .. half*8+7
        int tg = tile * TILE - HALO + j;
        bool valid = (tg >= 0) && (tg < T_LEN);
        float xv = valid ? x[(size_t)b * T_LEN + tg] : 0.0f;
        x_s[j] = xv;                         // both halves write same value (benign)
        unsigned* hp = &h_pack[j * HS + half * 8];
        #pragma unroll
        for (int q = 0; q < 4; ++q) {
            int ch = (half * 8 + 2 * q) * 2; // first of 4 consecutive channels
            float f0 = relu(fmaf(xv, w_init[ch],     b_init[ch]));
            float f1 = relu(fmaf(xv, w_init[ch + 1], b_init[ch + 1]));
            float f2 = relu(fmaf(xv, w_init[ch + 2], b_init[ch + 2]));
            float f3 = relu(fmaf(xv, w_init[ch + 3], b_init[ch + 3]));
            uint2 pk;
            pk.x = valid ? packh(f0, f1) : 0u;
            pk.y = valid ? packh(f2, f3) : 0u;
            *(uint2*)(hp + 2 * q) = pk;
        }
    }
    __syncthreads();    // drains vmcnt too -> iter-0 weight DMA landed

    #pragma unroll
    for (int i = 0; i < NBLK; ++i) {
        const int d = 1 << i;
        const unsigned* cur = &h_pack[(i & 1) * HBUF];
        unsigned*       nxt = &h_pack[((i + 1) & 1) * HBUF];
        volatile unsigned* vnxt = (volatile unsigned*)nxt;
        const int row0a = wv * 32;
        const int row0b = wv * 32 + 16;
        const bool ilast = (i == NBLK - 1);

        // iter-invariant reads (shared by both segments; was read per segment)
        half8 skw[2];
        skw[0] = *(const half8*)(wstage + STG_SKIP + (lane << 2));
        skw[1] = *(const half8*)(wstage + STG_SKIP + 256 + (lane << 2));
        float2 btv = *(const float2*)&bias_s[0 * NBLK * 32 + i * 32 + 2 * col0];
        float2 bsv = *(const float2*)&bias_s[1 * NBLK * 32 + i * 32 + 2 * col0];
        float2 bkv = *(const float2*)&bias_s[2 * NBLK * 32 + i * 32 + 2 * col0];

        // ---- front half: conv(0) -> gates/z(0) -> conv(1) -> gates/z(1) -> za reads
        unsigned hold0[4], hold1[4];
        {
            f32x4 acc[4];
            #pragma unroll
            for (int nt = 0; nt < 4; ++nt) acc[nt] = (f32x4){0.f, 0.f, 0.f, 0.f};
            CONV_SEG(row0a, acc, hold0);
            GATE_Z(row0a, acc);          // acc consumed -> only 4 packed dwords live
        }
        {
            f32x4 acc[4];
            #pragma unroll
            for (int nt = 0; nt < 4; ++nt) acc[nt] = (f32x4){0.f, 0.f, 0.f, 0.f};
            CONV_SEG(row0b, acc, hold1);
            GATE_Z(row0b, acc);
        }
        AFR az0, az1;
        ZA_READ(row0a, az0);             // issued pre-barrier: latency hides
        ZA_READ(row0b, az1);             // under the barrier's lgkm drain

        // staging barrier: all wstage reads of iter i done in every wave ->
        // safe to overwrite with iter i+1 weights; DMA flies under the back
        // half and lands at the iter-end barrier's vmcnt drain.
        if (i + 1 < NBLK) {
            __syncthreads();
            STAGE_ITER(i + 1);
        }

        // ---- back half: skip MFMAs + h updates (own rows only)
        {
            f32x4 s0 = (f32x4){0.f, 0.f, 0.f, 0.f}, s1 = (f32x4){0.f, 0.f, 0.f, 0.f};
            s0 = MFMA(az0.v, skw[0], s0);
            s1 = MFMA(az0.v, skw[1], s1);
            H_UPDATE(row0a, hold0, s0, s1, ilast);
        }
        {
            f32x4 s0 = (f32x4){0.f, 0.f, 0.f, 0.f}, s1 = (f32x4){0.f, 0.f, 0.f, 0.f};
            s0 = MFMA(az1.v, skw[0], s0);
            s1 = MFMA(az1.v, skw[1], s1);
            H_UPDATE(row0b, hold1, s0, s1, ilast);
        }

        // iter-end barrier: nxt complete + weight DMA drained. Not needed at
        // i=5: the final section reads only own-wave rows of ybuf.
        if (i + 1 < NBLK) __syncthreads();
    }

    // ---- final 1x1 conv via MFMA on y (buf0 after 6 iters; own-wave rows) ----
    // Issue all w_dense loads FIRST (clamped addresses, always in-bounds) so the
    // ~900cy cold-HBM latency overlaps the final-conv MFMAs + epilogue math.
    float4 wd[2][4];
    #pragma unroll
    for (int mt = 0; mt < 2; ++mt) {
        #pragma unroll
        for (int reg = 0; reg < 4; ++reg) {
            int row = wv * 32 + 16 * mt + 4 * g4 + reg;
            int tgr = tile * TILE - HALO + row;
            tgr = tgr < 0 ? 0 : (tgr > T_LEN - 1 ? T_LEN - 1 : tgr);
            wd[mt][reg] = *(const float4*)&w_dense[((size_t)tgr * 32 + 2 * col0) * 2];
        }
    }

    const unsigned* ybuf = &h_pack[(NBLK & 1) * HBUF];
    half8 fw[2];
    #pragma unroll
    for (int nt = 0; nt < 2; ++nt)
        fw[nt] = *(const half8*)(wsB + WS_FIN + nt * 256 + lane * 4);
    float2 bfv = *(const float2*)&b_final[2 * col0];
    float pa = 0.0f, pb = 0.0f;

    #pragma unroll
    for (int mt = 0; mt < 2; ++mt) {
        const unsigned* ya = ybuf + (wv * 32 + 16 * mt + col0) * HS + g4 * 4;
        AFR ay; ay.u2[0] = *(const uint2*)ya; ay.u2[1] = *(const uint2*)(ya + 2);
        f32x4 f0 = (f32x4){0.f, 0.f, 0.f, 0.f}, f1 = (f32x4){0.f, 0.f, 0.f, 0.f};
        f0 = MFMA(ay.v, fw[0], f0);
        f1 = MFMA(ay.v, fw[1], f1);
        #pragma unroll
        for (int reg = 0; reg < 4; ++reg) {
            int row = wv * 32 + 16 * mt + 4 * g4 + reg;
            if (row >= HALO && row < HALO + TILE) {
                float v0 = relu(f0[reg] + bfv.x);
                float v1 = relu(f1[reg] + bfv.y);
                float4 wv4 = wd[mt][reg];
                pa = fmaf(v0, wv4.x, pa); pb = fmaf(v0, wv4.y, pb);
                pa = fmaf(v1, wv4.z, pa); pb = fmaf(v1, wv4.w, pb);
            }
        }
    }

    // block reduction -> logits; last-arriving block does the softmax.
    // Tail parallelized across wave-0 lanes (3 atomic RTs vs 19 serialized).
    #pragma unroll
    for (int off = 32; off > 0; off >>= 1) {
        pa += __shfl_down(pa, off);
        pb += __shfl_down(pb, off);
    }
    if (lane == 0) { red[wv][0] = pa; red[wv][1] = pb; }
    __syncthreads();
    if (wv == 0) {
        if (lane < 2) {
            float s = 0.0f;
            #pragma unroll
            for (int w = 0; w < NWAVE; ++w) s += red[w][lane];
            atomicAdd(&logits[b * 2 + lane], s);
        }
        __threadfence();                       // release: logits adds before counter
        unsigned arrived = 0u;
        if (lane == 0) arrived = atomicAdd(counter, 1u);
        arrived = __builtin_amdgcn_readfirstlane(arrived);
        if (arrived == (unsigned)(NBATCH * NTILES - 1)) {
            __threadfence();                   // acquire
            float l = 0.0f;
            if (lane < 16)
                l = atomicAdd(&logits[lane], 0.0f) + b_dense[lane & 1];
            float lx = __shfl_xor(l, 1);
            float m  = fmaxf(l, lx);
            float e  = __expf(l - m);
            float ex = __shfl_xor(e, 1);
            float r  = e * __builtin_amdgcn_rcpf(e + ex);
            if (lane < 16) out[lane] = r;
        }
    }
    #undef STAGE_ITER
    #undef CONV_SEG
    #undef GATE_Z
    #undef ZA_READ
    #undef H_UPDATE
}

extern "C" void kernel_launch(void* const* d_in, const int* in_sizes, int n_in,
                              void* d_out, int out_size, void* d_ws, size_t ws_size,
                              hipStream_t stream) {
    const float* x       = (const float*)d_in[0];
    const float* w_init  = (const float*)d_in[1];
    const float* b_init  = (const float*)d_in[2];
    const float* w_tanh  = (const float*)d_in[3];
    const float* b_tanh  = (const float*)d_in[4];
    const float* w_sig   = (const float*)d_in[5];
    const float* b_sig   = (const float*)d_in[6];
    const float* w_skip  = (const float*)d_in[7];
    const float* b_skip  = (const float*)d_in[8];
    const float* w_final = (const float*)d_in[9];
    const float* b_final = (const float*)d_in[10];
    const float* w_dense = (const float*)d_in[11];
    const float* b_dense = (const float*)d_in[12];

    unsigned* wsB     = (unsigned*)d_ws;
    float*    logits  = (float*)d_ws + WS_LOG;
    unsigned* counter = (unsigned*)d_ws + WS_CNT;

    wavenet_prep<<<(PREP_TOT + 255) / 256, 256, 0, stream>>>(w_tanh, w_sig, w_skip, w_final, wsB);
    wavenet_main<<<NBATCH * NTILES, NTHR, 0, stream>>>(
        x, w_init, b_init, b_tanh, b_sig, b_skip, b_final, b_dense, w_dense,
        wsB, logits, counter, (float*)d_out);
}

// Round 5
// 120.224 us; speedup vs baseline: 1.3011x; 1.3011x over previous
//
#include <hip/hip_runtime.h>
#include <math.h>

#define T_LEN   16384
#define NBATCH  8
#define NBLK    6
#define TILE    256
#define HALO    63
#define NTHR    768          // 12 waves; each wave owns 32 rows (2 m-tiles)
#define NWAVE   12
#define NROWS   384          // TILE + 2*HALO = 382, padded to 384
#define NTILES  64
#define HS      18           // f16 row stride in dwords (72 B)
#define HBUF    (NROWS * HS) // one h buffer in dwords

// workspace layout (dwords)
#define WS_CONV 0             // [i6][tap3][nt4][lane64][dw4] = 18432
#define WS_SKIP 18432         // [i6][nt2][lane64][dw4]      = 3072
#define WS_FIN  21504         // [nt2][lane64][dw4]          = 512
#define WS_LOG  22016         // 16 floats logits
#define WS_CNT  22032         // 1 uint completion counter
#define PREP_N  22016
#define PREP_TOT 22036

// per-iter LDS weight stage: 12 conv chunks + 2 skip chunks, 256 dw each
#define STG_CONV 0            // [tap3][nt4][lane64][dw4] = 3072 dw
#define STG_SKIP 3072         // [nt2][lane64][dw4]       = 512 dw
#define STG_TOT  3584         // 14336 B

typedef _Float16 half8 __attribute__((ext_vector_type(8)));
typedef __fp16  fp16x2 __attribute__((ext_vector_type(2)));
typedef float f32x4  __attribute__((ext_vector_type(4)));

union HPK { unsigned u; _Float16 h[2]; fp16x2 pk; };
union AFR { uint2 u2[2]; half8 v; };

__device__ __forceinline__ unsigned packh(float a, float b) {   // 1x v_cvt_pkrtz_f16_f32
    HPK r; r.pk = __builtin_amdgcn_cvt_pkrtz(a, b); return r.u;
}
__device__ __forceinline__ float f16a(unsigned p) { HPK r; r.u = p; return (float)r.h[0]; }
__device__ __forceinline__ float f16b(unsigned p) { HPK r; r.u = p; return (float)r.h[1]; }

// tanh(a)*sigmoid(b), overflow-safe, 3 quarter-rate ops (2 exp + 1 rcp)
__device__ __forceinline__ float gated(float a, float b) {
    float ea  = __expf(-2.0f * fabsf(a));      // (0,1]
    float fb  = __expf(-b);
    float num = 1.0f - ea;
    float den = (1.0f + ea) * (1.0f + fb);
    float t   = num * __builtin_amdgcn_rcpf(den);
    return __builtin_copysignf(t, a);
}
__device__ __forceinline__ float relu(float x) { return fmaxf(x, 0.0f); }

// async global->LDS DMA, 16B per lane, wave-linear dest (base + lane*16)
__device__ __forceinline__ void gl_lds16(const unsigned* g, unsigned* l) {
    __builtin_amdgcn_global_load_lds(
        (const __attribute__((address_space(1))) void*)g,
        (__attribute__((address_space(3))) void*)l, 16, 0, 0);
}

#define MFMA(a, b, c) __builtin_amdgcn_mfma_f32_16x16x32_f16((a), (b), (c), 0, 0, 0)

// ---------------- weight prep: fp32 -> f16 B-fragments (permuted cols) ----------------
__global__ void wavenet_prep(const float* __restrict__ wt, const float* __restrict__ wsg,
                             const float* __restrict__ wsk, const float* __restrict__ wfin,
                             unsigned* __restrict__ out)
{
    int id = blockIdx.x * 256 + threadIdx.x;
    if (id >= PREP_TOT) return;
    if (id >= PREP_N) { out[id] = 0u; return; }   // zero logits + counter
    int dw = id & 3, lane = (id >> 2) & 63;
    int g = lane >> 4, nlo = lane & 15;
    int k0 = g * 8 + dw * 2, k1 = k0 + 1;
    float v0, v1;
    if (id < WS_SKIP) {
        int nt = (id >> 8) & 3; int q = id >> 10;
        int tap = q % 3, i = q / 3;
        int chan = 2 * nlo + (nt & 1);
        const float* src = (nt < 2) ? wt : wsg;
        v0 = src[((i * 3 + tap) * 32 + k0) * 32 + chan];
        v1 = src[((i * 3 + tap) * 32 + k1) * 32 + chan];
    } else if (id < WS_FIN) {
        int t = id - WS_SKIP;
        int nt = (t >> 8) & 1; int i = t >> 9;
        int chan = 2 * nlo + nt;
        v0 = wsk[(i * 32 + k0) * 32 + chan];
        v1 = wsk[(i * 32 + k1) * 32 + chan];
    } else {
        int t = id - WS_FIN;
        int nt = (t >> 8) & 1;
        int chan = 2 * nlo + nt;
        v0 = wfin[k0 * 32 + chan];
        v1 = wfin[k1 * 32 + chan];
    }
    HPK r; r.h[0] = (_Float16)v0; r.h[1] = (_Float16)v1;   // RNE for weights
    out[id] = r.u;
}

// ---------------- main fused kernel ----------------
// (768,6): cap 85 unified regs/wave -> 6 waves/SIMD -> 2 blocks/CU (24 waves).
// Per-m conv split keeps only 16 acc AGPRs live (un-split 32-acc spills, r16).
// r20: per-iter weights staged via global_load_lds (prefetch 1 iter ahead).
// r22 (this round): 2-segment pipeline ordered by the STAGING BARRIER itself.
// Per iter: conv(0)+gates/z(0), conv(1)+gates/z(1)  [schedulable against each
// other], then __syncthreads (drains lgkm -> z visible; full compiler fence),
// then DMA issue + za reads + skip MFMAs + h updates, then iter-end barrier.
// r21's volatile-pointer variant of this DIED (FETCH+WRITE 188MB = scratch
// spill round-trips; volatile defeated LDS addrspace inference + scheduling).
// NEVER use volatile casts on LDS pointers for ordering -- barriers/fences only.
__global__ __launch_bounds__(NTHR, 6)
void wavenet_main(const float* __restrict__ x,
                  const float* __restrict__ w_init, const float* __restrict__ b_init,
                  const float* __restrict__ b_tanh, const float* __restrict__ b_sig,
                  const float* __restrict__ b_skip, const float* __restrict__ b_final,
                  const float* __restrict__ b_dense,
                  const float* __restrict__ w_dense,
                  const unsigned* __restrict__ wsB,
                  float* __restrict__ logits, unsigned* __restrict__ counter,
                  float* __restrict__ out)
{
    __shared__ unsigned h_pack[2 * HBUF];      // double-buffered, 55296 B
    __shared__ unsigned wstage[STG_TOT];       // per-iter weight stage, 14336 B
    __shared__ float x_s[NROWS];               // 1536 B
    __shared__ float bias_s[3 * NBLK * 32];    // [t/s/k][i][ch], 2304 B
    __shared__ float wib_s[64];                // w_init[0..31], b_init[0..31]
    __shared__ float red[NWAVE][2];

    const int tid  = threadIdx.x;
    const int lane = tid & 63;
    const int wv   = tid >> 6;               // 0..11; wave owns rows [wv*32, wv*32+32)
    const int tile = blockIdx.x & (NTILES - 1);
    const int b    = blockIdx.x >> 6;
    const int col0 = lane & 15;
    const int g4   = lane >> 4;

    // stage iter-`it` weights: wave wv takes conv chunk wv, waves 0/1 also skip chunks
    #define STAGE_ITER(it) do {                                                   \
        const unsigned* _s = wsB + (it) * 3072 + wv * 256 + (lane << 2);          \
        gl_lds16(_s, wstage + wv * 256 + (lane << 2));                            \
        if (wv < 2) {                                                             \
            const unsigned* _s2 = wsB + WS_SKIP + (it) * 512 + wv * 256 + (lane << 2); \
            gl_lds16(_s2, wstage + STG_SKIP + wv * 256 + (lane << 2));            \
        }                                                                         \
    } while (0)

    // conv GEMM for one 16-row segment: [16 x 96] x [96 x 64], single-product f16
    #define CONV_SEG(ROW0, ACC, HOLD) do {                                        \
        _Pragma("unroll")                                                         \
        for (int tap = 0; tap < 3; ++tap) {                                       \
            half8 bw[4];                                                          \
            _Pragma("unroll")                                                     \
            for (int nt = 0; nt < 4; ++nt)                                        \
                bw[nt] = *(const half8*)(wstage + (tap * 4 + nt) * 256 + (lane << 2)); \
            int r = (ROW0) + (tap - 1) * d + col0;                                \
            r = r < 0 ? 0 : (r > NROWS - 1 ? NROWS - 1 : r);                      \
            const unsigned* hp = cur + r * HS + g4 * 4;                           \
            AFR a; a.u2[0] = *(const uint2*)hp; a.u2[1] = *(const uint2*)(hp + 2);\
            _Pragma("unroll")                                                     \
            for (int nt = 0; nt < 4; ++nt)                                        \
                (ACC)[nt] = MFMA(a.v, bw[nt], (ACC)[nt]);                         \
        }                                                                         \
        _Pragma("unroll")                                                         \
        for (int reg = 0; reg < 4; ++reg)                                         \
            (HOLD)[reg] = cur[((ROW0) + 4 * g4 + reg) * HS + col0];               \
    } while (0)

    // gates + z-write for one segment (consumes ACC into 4 packed dwords in nxt)
    #define GATE_Z(ROW0, ACC) do {                                                \
        _Pragma("unroll")                                                         \
        for (int reg = 0; reg < 4; ++reg) {                                       \
            float z0 = gated((ACC)[0][reg] + btv.x, (ACC)[2][reg] + bsv.x);       \
            float z1 = gated((ACC)[1][reg] + btv.y, (ACC)[3][reg] + bsv.y);       \
            nxt[((ROW0) + 4 * g4 + reg) * HS + col0] = packh(z0, z1);             \
        }                                                                         \
    } while (0)

    // za gather (A-fragment of z for the skip MFMA); plain LDS reads
    #define ZA_READ(ROW0, AZ) do {                                                \
        const unsigned* _p = nxt + ((ROW0) + col0) * HS + g4 * 4;                 \
        (AZ).u2[0] = *(const uint2*)_p; (AZ).u2[1] = *(const uint2*)(_p + 2);     \
    } while (0)

    // skip epilogue + h update into nxt (own rows only)
    #define H_UPDATE(ROW0, HOLD, S0, S1, ILAST) do {                              \
        _Pragma("unroll")                                                         \
        for (int reg = 0; reg < 4; ++reg) {                                       \
            const int row = (ROW0) + 4 * g4 + reg;                                \
            float sk0 = relu((S0)[reg] + bkv.x);                                  \
            float sk1 = relu((S1)[reg] + bkv.y);                                  \
            unsigned ph = (HOLD)[reg];                                            \
            float h0n = sk0 + f16a(ph);                                           \
            float h1n = sk1 + f16b(ph);                                           \
            unsigned pk;                                                          \
            if (!(ILAST)) {                                                       \
                int tgr = tile * TILE - HALO + row;                               \
                bool vr = (tgr >= 0) && (tgr < T_LEN);                            \
                pk = vr ? packh(h0n, h1n) : 0u;                                   \
            } else {                                                              \
                float2 wiv = *(const float2*)&wib_s[2 * col0];                    \
                float2 biv = *(const float2*)&wib_s[32 + 2 * col0];               \
                float xr  = x_s[row];                                             \
                float hi0 = relu(fmaf(xr, wiv.x, biv.x));                         \
                float hi1 = relu(fmaf(xr, wiv.y, biv.y));                         \
                pk = packh(relu(h0n - hi0), relu(h1n - hi1));                     \
            }                                                                     \
            nxt[row * HS + col0] = pk;                                            \
        }                                                                         \
    } while (0)

    // ---- issue DMA for iter-0 weights immediately (lands before first barrier drain) ----
    STAGE_ITER(0);

    // ---- stage biases + init weights into LDS (once) ----
    if (tid < 3 * NBLK * 32) {
        int which = tid / (NBLK * 32), r = tid % (NBLK * 32);
        float v = (which == 0) ? b_tanh[r] : (which == 1) ? b_sig[r] : b_skip[r];
        bias_s[tid] = v;
    } else if (tid < 3 * NBLK * 32 + 64) {
        int r = tid - 3 * NBLK * 32;
        wib_s[r] = (r < 32) ? w_init[r] : b_init[r - 32];
    }

    // ---- init conv (CIN=1) -> f16 h in buf0; 2 threads per row ----
    {
        int j    = tid >> 1;                 // row 0..383
        int half = tid & 1;                  // dwords half*8 .. half*8+7
        int tg = tile * TILE - HALO + j;
        bool valid = (tg >= 0) && (tg < T_LEN);
        float xv = valid ? x[(size_t)b * T_LEN + tg] : 0.0f;
        x_s[j] = xv;                         // both halves write same value (benign)
        unsigned* hp = &h_pack[j * HS + half * 8];
        #pragma unroll
        for (int q = 0; q < 4; ++q) {
            int ch = (half * 8 + 2 * q) * 2; // first of 4 consecutive channels
            float f0 = relu(fmaf(xv, w_init[ch],     b_init[ch]));
            float f1 = relu(fmaf(xv, w_init[ch + 1], b_init[ch + 1]));
            float f2 = relu(fmaf(xv, w_init[ch + 2], b_init[ch + 2]));
            float f3 = relu(fmaf(xv, w_init[ch + 3], b_init[ch + 3]));
            uint2 pk;
            pk.x = valid ? packh(f0, f1) : 0u;
            pk.y = valid ? packh(f2, f3) : 0u;
            *(uint2*)(hp + 2 * q) = pk;
        }
    }
    __syncthreads();    // drains vmcnt too -> iter-0 weight DMA landed

    #pragma unroll
    for (int i = 0; i < NBLK; ++i) {
        const int d = 1 << i;
        const unsigned* cur = &h_pack[(i & 1) * HBUF];
        unsigned*       nxt = &h_pack[((i + 1) & 1) * HBUF];
        const int row0a = wv * 32;
        const int row0b = wv * 32 + 16;
        const bool ilast = (i == NBLK - 1);

        // iter-invariant reads (shared by both segments)
        half8 skw[2];
        skw[0] = *(const half8*)(wstage + STG_SKIP + (lane << 2));
        skw[1] = *(const half8*)(wstage + STG_SKIP + 256 + (lane << 2));
        float2 btv = *(const float2*)&bias_s[0 * NBLK * 32 + i * 32 + 2 * col0];
        float2 bsv = *(const float2*)&bias_s[1 * NBLK * 32 + i * 32 + 2 * col0];
        float2 bkv = *(const float2*)&bias_s[2 * NBLK * 32 + i * 32 + 2 * col0];

        // ---- front half: both convs + gates + z writes (freely schedulable;
        // cur/nxt are disjoint compile-time LDS ranges after full unroll)
        unsigned hold0[4], hold1[4];
        {
            f32x4 acc[4];
            #pragma unroll
            for (int nt = 0; nt < 4; ++nt) acc[nt] = (f32x4){0.f, 0.f, 0.f, 0.f};
            CONV_SEG(row0a, acc, hold0);
            GATE_Z(row0a, acc);          // acc consumed -> only 4 packed dwords live
        }
        {
            f32x4 acc[4];
            #pragma unroll
            for (int nt = 0; nt < 4; ++nt) acc[nt] = (f32x4){0.f, 0.f, 0.f, 0.f};
            CONV_SEG(row0b, acc, hold1);
            GATE_Z(row0b, acc);
        }

        // staging barrier: (a) all waves' wstage reads of iter i done -> safe to
        // overwrite with iter i+1 weights; (b) full compiler+HW fence ordering
        // the z ds_writes above before the za ds_reads below. Last iter has no
        // barrier: z->za is same-wave (own 16-row segments), in-order DS +
        // a compiler-only fence suffice (r17/r20-proven pattern).
        if (!ilast) {
            __syncthreads();
            STAGE_ITER(i + 1);           // DMA flies under back half; lands at
        } else {                         // the iter-end barrier's vmcnt drain
            asm volatile("" ::: "memory");
        }

        // ---- back half: za reads + skip MFMAs + h updates (own rows only).
        // za(1) latency hides under skip-MFMA(0)/H_UPDATE(0).
        AFR az0, az1;
        ZA_READ(row0a, az0);
        ZA_READ(row0b, az1);
        {
            f32x4 s0 = (f32x4){0.f, 0.f, 0.f, 0.f}, s1 = (f32x4){0.f, 0.f, 0.f, 0.f};
            s0 = MFMA(az0.v, skw[0], s0);
            s1 = MFMA(az0.v, skw[1], s1);
            H_UPDATE(row0a, hold0, s0, s1, ilast);
        }
        {
            f32x4 s0 = (f32x4){0.f, 0.f, 0.f, 0.f}, s1 = (f32x4){0.f, 0.f, 0.f, 0.f};
            s0 = MFMA(az1.v, skw[0], s0);
            s1 = MFMA(az1.v, skw[1], s1);
            H_UPDATE(row0b, hold1, s0, s1, ilast);
        }

        // iter-end barrier: nxt complete across waves + weight DMA drained.
        // Dead at i=5: the final section reads only own-wave rows of ybuf.
        if (!ilast) __syncthreads();
    }

    // ---- final 1x1 conv via MFMA on y (buf0 after 6 iters; own-wave rows) ----
    // Issue all w_dense loads FIRST (clamped addresses, always in-bounds) so the
    // ~900cy cold-HBM latency overlaps the final-conv MFMAs + epilogue math.
    float4 wd[2][4];
    #pragma unroll
    for (int mt = 0; mt < 2; ++mt) {
        #pragma unroll
        for (int reg = 0; reg < 4; ++reg) {
            int row = wv * 32 + 16 * mt + 4 * g4 + reg;
            int tgr = tile * TILE - HALO + row;
            tgr = tgr < 0 ? 0 : (tgr > T_LEN - 1 ? T_LEN - 1 : tgr);
            wd[mt][reg] = *(const float4*)&w_dense[((size_t)tgr * 32 + 2 * col0) * 2];
        }
    }

    const unsigned* ybuf = &h_pack[(NBLK & 1) * HBUF];
    half8 fw[2];
    #pragma unroll
    for (int nt = 0; nt < 2; ++nt)
        fw[nt] = *(const half8*)(wsB + WS_FIN + nt * 256 + lane * 4);
    float2 bfv = *(const float2*)&b_final[2 * col0];
    float pa = 0.0f, pb = 0.0f;

    #pragma unroll
    for (int mt = 0; mt < 2; ++mt) {
        const unsigned* ya = ybuf + (wv * 32 + 16 * mt + col0) * HS + g4 * 4;
        AFR ay; ay.u2[0] = *(const uint2*)ya; ay.u2[1] = *(const uint2*)(ya + 2);
        f32x4 f0 = (f32x4){0.f, 0.f, 0.f, 0.f}, f1 = (f32x4){0.f, 0.f, 0.f, 0.f};
        f0 = MFMA(ay.v, fw[0], f0);
        f1 = MFMA(ay.v, fw[1], f1);
        #pragma unroll
        for (int reg = 0; reg < 4; ++reg) {
            int row = wv * 32 + 16 * mt + 4 * g4 + reg;
            if (row >= HALO && row < HALO + TILE) {
                float v0 = relu(f0[reg] + bfv.x);
                float v1 = relu(f1[reg] + bfv.y);
                float4 wv4 = wd[mt][reg];
                pa = fmaf(v0, wv4.x, pa); pb = fmaf(v0, wv4.y, pb);
                pa = fmaf(v1, wv4.z, pa); pb = fmaf(v1, wv4.w, pb);
            }
        }
    }

    // block reduction -> logits; last-arriving block does the softmax.
    // Tail parallelized across wave-0 lanes (3 atomic RTs vs 19 serialized).
    #pragma unroll
    for (int off = 32; off > 0; off >>= 1) {
        pa += __shfl_down(pa, off);
        pb += __shfl_down(pb, off);
    }
    if (lane == 0) { red[wv][0] = pa; red[wv][1] = pb; }
    __syncthreads();
    if (wv == 0) {
        if (lane < 2) {
            float s = 0.0f;
            #pragma unroll
            for (int w = 0; w < NWAVE; ++w) s += red[w][lane];
            atomicAdd(&logits[b * 2 + lane], s);
        }
        __threadfence();                       // release: logits adds before counter
        unsigned arrived = 0u;
        if (lane == 0) arrived = atomicAdd(counter, 1u);
        arrived = __builtin_amdgcn_readfirstlane(arrived);
        if (arrived == (unsigned)(NBATCH * NTILES - 1)) {
            __threadfence();                   // acquire
            float l = 0.0f;
            if (lane < 16)
                l = atomicAdd(&logits[lane], 0.0f) + b_dense[lane & 1];
            float lx = __shfl_xor(l, 1);
            float m  = fmaxf(l, lx);
            float e  = __expf(l - m);
            float ex = __shfl_xor(e, 1);
            float r  = e * __builtin_amdgcn_rcpf(e + ex);
            if (lane < 16) out[lane] = r;
        }
    }
    #undef STAGE_ITER
    #undef CONV_SEG
    #undef GATE_Z
    #undef ZA_READ
    #undef H_UPDATE
}

extern "C" void kernel_launch(void* const* d_in, const int* in_sizes, int n_in,
                              void* d_out, int out_size, void* d_ws, size_t ws_size,
                              hipStream_t stream) {
    const float* x       = (const float*)d_in[0];
    const float* w_init  = (const float*)d_in[1];
    const float* b_init  = (const float*)d_in[2];
    const float* w_tanh  = (const float*)d_in[3];
    const float* b_tanh  = (const float*)d_in[4];
    const float* w_sig   = (const float*)d_in[5];
    const float* b_sig   = (const float*)d_in[6];
    const float* w_skip  = (const float*)d_in[7];
    const float* b_skip  = (const float*)d_in[8];
    const float* w_final = (const float*)d_in[9];
    const float* b_final = (const float*)d_in[10];
    const float* w_dense = (const float*)d_in[11];
    const float* b_dense = (const float*)d_in[12];

    unsigned* wsB     = (unsigned*)d_ws;
    float*    logits  = (float*)d_ws + WS_LOG;
    unsigned* counter = (unsigned*)d_ws + WS_CNT;

    wavenet_prep<<<(PREP_TOT + 255) / 256, 256, 0, stream>>>(w_tanh, w_sig, w_skip, w_final, wsB);
    wavenet_main<<<NBATCH * NTILES, NTHR, 0, stream>>>(
        x, w_init, b_init, b_tanh, b_sig, b_skip, b_final, b_dense, w_dense,
        wsB, logits, counter, (float*)d_out);
}